// Round 13
// baseline (127.899 us; speedup 1.0000x reference)
//
#include <hip/hip_runtime.h>
#include <math.h>

#define BLn 16
#define Nn 256
#define Tn 32
#define Cn 256
#define Hn 4
#define HDn 64
#define KREL 32

typedef float f32x4 __attribute__((ext_vector_type(4)));
typedef __bf16 bf16x8 __attribute__((ext_vector_type(8)));
typedef _Float16 f16x4 __attribute__((ext_vector_type(4)));
typedef _Float16 f16x2 __attribute__((ext_vector_type(2)));

#define MFMA16(a, b, c) __builtin_amdgcn_mfma_f32_16x16x32_bf16(a, b, c, 0, 0, 0)
#define MFMA16H(a, b, c) __builtin_amdgcn_mfma_f32_16x16x16f16(a, b, c, 0, 0, 0)

__device__ __forceinline__ float gelu_exact(float x) {
    return 0.5f * x * (1.0f + erff(x * 0.70710678118654752440f));
}

// packed-f16 gelu (validated r8/r12, absmax 0.031)
__device__ __forceinline__ f16x2 gelu_pk(f16x2 x) {
    const f16x2 P4 = {(_Float16)4.0f, (_Float16)4.0f};
    const f16x2 M4 = {(_Float16)-4.0f, (_Float16)-4.0f};
    const f16x2 C0 = {(_Float16)0.833076f, (_Float16)0.833076f};
    const f16x2 C1 = {(_Float16)-0.139388f, (_Float16)-0.139388f};
    const f16x2 C2 = {(_Float16)0.013040f, (_Float16)0.013040f};
    const f16x2 C3 = {(_Float16)-0.000413f, (_Float16)-0.000413f};
    const f16x2 HF = {(_Float16)0.5f, (_Float16)0.5f};
    const f16x2 ONE = {(_Float16)1.0f, (_Float16)1.0f};
    const f16x2 ZERO = {(_Float16)0.0f, (_Float16)0.0f};
    f16x2 xc = __builtin_elementwise_min(__builtin_elementwise_max(x, M4), P4);
    f16x2 v = xc * xc;
    f16x2 w = C3 * v + C2;
    w = w * v + C1;
    w = w * v + C0;
    f16x2 t = w * xc;
    f16x2 s = t * HF + HF;
    s = __builtin_elementwise_min(__builtin_elementwise_max(s, ZERO), ONE);
    return x * s;
}

// ---------------- fused prep: ln(wave-per-row) | knn | sizes | headw | W transposes ----
__global__ void __launch_bounds__(256) k_prep(
    const float* __restrict__ x, const float* __restrict__ ln_g, const float* __restrict__ ln_b,
    __bf16* __restrict__ xnb, const float* __restrict__ centers, const int* __restrict__ obj,
    unsigned char* __restrict__ knn, const float* __restrict__ corners,
    float* __restrict__ sizes, const float* __restrict__ lang, const float* __restrict__ Wt1,
    const float* __restrict__ bt1, const float* __restrict__ Wt2, const float* __restrict__ bt2,
    float* __restrict__ headw, const float* __restrict__ W_qkv, __bf16* __restrict__ wqT,
    const float* __restrict__ W_proj, __bf16* __restrict__ wpT) {
    __shared__ float4 d4[64];
    __shared__ float sm1[Nn];
    __shared__ float T[64][65];
    float* sm0 = (float*)d4;
    int blk = blockIdx.x;
    int tid = threadIdx.x;

    if (blk < 1024) {  // ---- LayerNorm: 1 wave = 1 row, no LDS, no barriers ----
        int row = blk * 4 + (tid >> 6);
        int l = tid & 63;
        float4 v = ((const float4*)(x + (size_t)row * Cn))[l];
        float s = v.x + v.y + v.z + v.w;
        float q = v.x * v.x + v.y * v.y + v.z * v.z + v.w * v.w;
        for (int m = 32; m > 0; m >>= 1) {
            s += __shfl_xor(s, m, 64);
            q += __shfl_xor(q, m, 64);
        }
        float mu = s * (1.0f / Cn);
        float var = q * (1.0f / Cn) - mu * mu;
        float r = rsqrtf(var + 1e-5f);
        float4 g = ((const float4*)ln_g)[l];
        float4 be = ((const float4*)ln_b)[l];
        __bf16 ob[4];
        ob[0] = (__bf16)((v.x - mu) * r * g.x + be.x);
        ob[1] = (__bf16)((v.y - mu) * r * g.y + be.y);
        ob[2] = (__bf16)((v.z - mu) * r * g.z + be.z);
        ob[3] = (__bf16)((v.w - mu) * r * g.w + be.w);
        *(uint2*)(xnb + (size_t)row * Cn + l * 4) = *(uint2*)ob;
    } else if (blk < 5120) {  // ---- KNN + pair mask ----
        int bi = blk - 1024;
        int b = bi >> 8, i = bi & 255;
        int j = tid;
        float cx = centers[(b * Nn + i) * 3 + 0];
        float cy = centers[(b * Nn + i) * 3 + 1];
        float cz = centers[(b * Nn + i) * 3 + 2];
        float dx = centers[(b * Nn + j) * 3 + 0] - cx;
        float dy = centers[(b * Nn + j) * 3 + 1] - cy;
        float dz = centers[(b * Nn + j) * 3 + 2] - cz;
        float dd = sqrtf(dx * dx + dy * dy + dz * dz);
        sm0[j] = dd;
        __syncthreads();
        int rank = 0;
        for (int t4 = 0; t4 < 64; t4++) {
            float4 o = d4[t4];
            int t = t4 * 4;
            rank += (o.x < dd) || (o.x == dd && t + 0 < j);
            rank += (o.y < dd) || (o.y == dd && t + 1 < j);
            rank += (o.z < dd) || (o.z == dd && t + 2 < j);
            rank += (o.w < dd) || (o.w == dd && t + 3 < j);
        }
        bool m = (rank < KREL);
        m = m && (obj[b * Nn + i] != 0) && (obj[b * Nn + j] != 0);
        knn[(size_t)bi * Nn + j] = m ? 1 : 0;
    } else if (blk < 5136) {  // ---- sizes ----
        int b = blk - 5120, n = tid;
        const float* p = corners + (size_t)((b * Nn + n) * 8) * 3;
        float mn[3] = {1e30f, 1e30f, 1e30f}, mx[3] = {-1e30f, -1e30f, -1e30f};
        for (int v = 0; v < 8; v++)
            for (int d = 0; d < 3; d++) {
                float t = p[v * 3 + d];
                mn[d] = fminf(mn[d], t);
                mx[d] = fmaxf(mx[d], t);
            }
        for (int d = 0; d < 3; d++) sizes[(b * Nn + n) * 3 + d] = mx[d] - mn[d];
    } else if (blk < 5152) {  // ---- head weights ----
        int b = blk - 5136, c = tid;
        float s = 0.0f;
        for (int t = 0; t < Tn; t++) s += lang[((size_t)b * Tn + t) * Cn + c];
        sm0[c] = s * (1.0f / Tn);
        __syncthreads();
        float acc = bt1[c];
        for (int i = 0; i < Cn; i++) acc += sm0[i] * Wt1[i * Cn + c];
        sm1[c] = gelu_exact(acc);
        __syncthreads();
        if (c < Hn) {
            float a = bt2[c];
            for (int i = 0; i < Cn; i++) a += sm1[i] * Wt2[i * Hn + c];
            headw[b * Hn + c] = 1.0f / (1.0f + expf(-a));
        }
    } else if (blk < 5200) {  // ---- W_qkv^T -> bf16 [768 o][256 k] ----
        int t = blk - 5152;
        int kt = t & 3, ot = t >> 2;
        for (int itr = 0; itr < 16; itr++) {
            int idx = itr * 256 + tid;
            int r = idx >> 6, c = idx & 63;
            T[r][c] = W_qkv[(size_t)(kt * 64 + r) * 768 + ot * 64 + c];
        }
        __syncthreads();
        for (int itr = 0; itr < 16; itr++) {
            int idx = itr * 256 + tid;
            int r = idx >> 6, c = idx & 63;
            wqT[(size_t)(ot * 64 + r) * 256 + kt * 64 + c] = (__bf16)T[c][r];
        }
    } else {  // ---- W_proj^T -> bf16 [256 o][256 k] ----
        int t = blk - 5200;
        int kt = t & 3, ot = t >> 2;
        for (int itr = 0; itr < 16; itr++) {
            int idx = itr * 256 + tid;
            int r = idx >> 6, c = idx & 63;
            T[r][c] = W_proj[(size_t)(kt * 64 + r) * 256 + ot * 64 + c];
        }
        __syncthreads();
        for (int itr = 0; itr < 16; itr++) {
            int idx = itr * 256 + tid;
            int r = idx >> 6, c = idx & 63;
            wpT[(size_t)(ot * 64 + r) * 256 + kt * 64 + c] = (__bf16)T[c][r];
        }
    }
}

// ---------------- fused heavy kernel: geombias + qkv (V stored transposed) ----------------
__global__ void __launch_bounds__(256, 4) k_heavy(
    const float* __restrict__ centers, const float* __restrict__ sizes,
    const float* __restrict__ Wg1, const float* __restrict__ bg1,
    const float* __restrict__ Wg2, const float* __restrict__ bg2,
    const float* __restrict__ headw, const float* __restrict__ alphap,
    float* __restrict__ bias_eff, const __bf16* __restrict__ xnb,
    const __bf16* __restrict__ wqT, const float* __restrict__ bqkv,
    __bf16* __restrict__ qkvb) {
    __shared__ __align__(16) _Float16 fT[Nn][20];   // [j][k]  10240 B (aliased as V tile)
    __shared__ __align__(16) _Float16 W1T[Cn][20];  // [c][k]  10240 B
    __shared__ __align__(16) _Float16 W2T[16][264]; // [h][c] rows 4..15 zero, 8448 B

    int blk = blockIdx.x;
    int tid = threadIdx.x;

    if (blk >= 4096) {
        // ================= QKV path (bf16 MFMA, K=32) =================
        int t = blk - 4096;
        int ib = t & 63, y = t >> 6;
        int w = tid >> 6, l = tid & 63, lr = l & 15, lg = l >> 4;
        const __bf16* arow = xnb + (size_t)(ib * 64 + w * 16 + lr) * Cn;

        f32x4 acc[4];
#pragma unroll
        for (int ot = 0; ot < 4; ot++) acc[ot] = (f32x4){0.f, 0.f, 0.f, 0.f};
#pragma unroll
        for (int kc = 0; kc < 8; kc++) {
            bf16x8 af = *(const bf16x8*)(arow + kc * 32 + lg * 8);
#pragma unroll
            for (int ot = 0; ot < 4; ot++) {
                bf16x8 bfr = *(const bf16x8*)(wqT + (size_t)(y * 64 + ot * 16 + lr) * Cn +
                                              kc * 32 + lg * 8);
                acc[ot] = MFMA16(af, bfr, acc[ot]);
            }
        }
        int seg = y >> 2, h = y & 3;
        int bq = ib >> 2;  // batch (64-row slab lies within one batch)
        if (seg < 2) {
            // Q, K: [bh][n][d] layout
            __bf16* segp = qkvb + (size_t)seg * 1048576;
#pragma unroll
            for (int ot = 0; ot < 4; ot++) {
                float bo = bqkv[y * 64 + ot * 16 + lr];
#pragma unroll
                for (int r = 0; r < 4; r++) {
                    int ig = ib * 64 + w * 16 + lg * 4 + r;
                    int n = ig & 255;
                    segp[(((size_t)(bq * Hn + h)) * Nn + n) * HDn + ot * 16 + lr] =
                        (__bf16)(acc[ot][r] + bo);
                }
            }
        } else {
            // V: transpose via LDS (aliased over fT) -> vT[bh][d][n], coalesced stores
            __bf16(*Vl)[72] = (__bf16(*)[72])fT;  // 64 x 72 x 2B = 9216 B
            int nloc = w * 16 + lg * 4;
#pragma unroll
            for (int ot = 0; ot < 4; ot++) {
                int d = ot * 16 + lr;
                float bo = bqkv[y * 64 + d];
                __bf16 pb[4];
#pragma unroll
                for (int r = 0; r < 4; r++) pb[r] = (__bf16)(acc[ot][r] + bo);
                *(uint2*)&Vl[d][nloc] = *(uint2*)pb;
            }
            __syncthreads();
            int d = tid >> 2, q = tid & 3;
            __bf16* vT = qkvb + 2 * 1048576 + (size_t)(bq * Hn + h) * (HDn * Nn);
            int ncol = ((ib & 3) * 64) + q * 16;
            uint4 a0 = *(uint4*)&Vl[d][q * 16];
            uint4 a1 = *(uint4*)&Vl[d][q * 16 + 8];
            *(uint4*)(vT + (size_t)d * Nn + ncol) = a0;
            *(uint4*)(vT + (size_t)d * Nn + ncol + 8) = a1;
        }
        return;
    }

    // ================= geombias path (EXACT r12) =================
    int b = blk >> 8, i = blk & 255;

    {
        int c = tid;
        _Float16 t1[20];
#pragma unroll
        for (int k = 0; k < 12; k++) t1[k] = (_Float16)Wg1[k * Cn + c];
        t1[12] = (_Float16)bg1[c];
#pragma unroll
        for (int k = 13; k < 20; k++) t1[k] = (_Float16)0.f;
#pragma unroll
        for (int q = 0; q < 5; q++) *(uint2*)&W1T[c][q * 4] = *(uint2*)&t1[q * 4];
#pragma unroll
        for (int h = 0; h < 16; h++)
            W2T[h][c] = (h < Hn) ? (_Float16)Wg2[c * Hn + h] : (_Float16)0.f;
    }
    {
        int j = tid;
        float ci0 = centers[(b * Nn + i) * 3 + 0];
        float ci1 = centers[(b * Nn + i) * 3 + 1];
        float ci2 = centers[(b * Nn + i) * 3 + 2];
        float si0 = sizes[(b * Nn + i) * 3 + 0];
        float si1 = sizes[(b * Nn + i) * 3 + 1];
        float si2 = sizes[(b * Nn + i) * 3 + 2];
        float cj0 = centers[(b * Nn + j) * 3 + 0];
        float cj1 = centers[(b * Nn + j) * 3 + 1];
        float cj2 = centers[(b * Nn + j) * 3 + 2];
        float sj0 = sizes[(b * Nn + j) * 3 + 0];
        float sj1 = sizes[(b * Nn + j) * 3 + 1];
        float sj2 = sizes[(b * Nn + j) * 3 + 2];
        float rx = cj0 - ci0, ry = cj1 - ci1, rz = cj2 - ci2;
        float h2 = rx * rx + ry * ry;
        float dist = sqrtf(h2 + rz * rz);
        float horiz = sqrtf(h2);
        float f[16];
        f[0] = rx; f[1] = ry; f[2] = rz;
        f[3] = dist; f[4] = horiz;
        f[5] = rz / (dist + 1e-6f);
        f[6] = sj0 - si0; f[7] = sj1 - si1; f[8] = sj2 - si2;
        f[9] = sj0 / (si0 + 1e-6f);
        f[10] = sj1 / (si1 + 1e-6f);
        f[11] = sj2 / (si2 + 1e-6f);
        f[12] = 1.0f;  // bias feature -> W1 row 12 = bg1
        _Float16 tf[20];
#pragma unroll
        for (int k = 0; k < 13; k++) tf[k] = (_Float16)f[k];
#pragma unroll
        for (int k = 13; k < 20; k++) tf[k] = (_Float16)0.f;
#pragma unroll
        for (int q = 0; q < 5; q++) *(uint2*)&fT[j][q * 4] = *(uint2*)&tf[q * 4];
    }
    __syncthreads();

    int w = tid >> 6, l = tid & 63;
    int lr = l & 15, lg = l >> 4;
    int jw = w * 64;

    f32x4 zero4 = {0.f, 0.f, 0.f, 0.f};

    f16x4 bf_[4];
#pragma unroll
    for (int jt = 0; jt < 4; jt++) bf_[jt] = *(const f16x4*)&fT[jw + jt * 16 + lr][lg * 4];

    f32x4 pacc[4];
#pragma unroll
    for (int jt = 0; jt < 4; jt++) pacc[jt] = zero4;

#pragma unroll 2
    for (int cw = 0; cw < 16; cw++) {
        int cbase = cw * 16;
        f16x4 aw = *(const f16x4*)&W1T[cbase + lr][lg * 4];
        f16x4 b2 = *(const f16x4*)&W2T[lr][cbase + lg * 4];
#pragma unroll
        for (int jt = 0; jt < 4; jt++) {
            f32x4 acc = MFMA16H(aw, bf_[jt], zero4);
            f16x2 h01 = __builtin_bit_cast(f16x2, __builtin_amdgcn_cvt_pkrtz(acc[0], acc[1]));
            f16x2 h23 = __builtin_bit_cast(f16x2, __builtin_amdgcn_cvt_pkrtz(acc[2], acc[3]));
            h01 = gelu_pk(h01);
            h23 = gelu_pk(h23);
            f16x4 ga;
            ga[0] = h01[0]; ga[1] = h01[1]; ga[2] = h23[0]; ga[3] = h23[1];
            pacc[jt] = MFMA16H(ga, b2, pacc[jt]);
        }
    }

    float alpha = alphap[0];
    if (lr < Hn) {
        float hw_ = headw[b * Hn + lr];
        float bg = bg2[lr];
        float* dst = bias_eff + (((size_t)(b * Hn + lr)) * Nn + i) * Nn;
#pragma unroll
        for (int jt = 0; jt < 4; jt++) {
            f32x4 o4;
#pragma unroll
            for (int r = 0; r < 4; r++) o4[r] = alpha * hw_ * (pacc[jt][r] + bg);
            *(f32x4*)&dst[jw + jt * 16 + lg * 4] = o4;
        }
    }
}

// ---------------- attention + proj fused: block = 16 rows x 4 heads (wave = head) ------
// grid 256: blk>>4 = b, blk&15 = it (16-row slab). PV reads vT direct from global.
__global__ void __launch_bounds__(256) k_attn(const __bf16* __restrict__ qkvb,
                                              const float* __restrict__ bias_eff,
                                              const unsigned char* __restrict__ knn,
                                              float* __restrict__ attn_out,
                                              const __bf16* __restrict__ wpT,
                                              const float* __restrict__ bp,
                                              const float* __restrict__ x,
                                              float* __restrict__ xout) {
    __shared__ __bf16 Plds[4][16][136];  // per-wave P slab 17408 B
    __shared__ __bf16 htile[16][264];    // hout tile [i][c]  8448 B
    int blk = blockIdx.x;
    int b = blk >> 4, it = blk & 15;
    int tid = threadIdx.x;
    int w = tid >> 6, l = tid & 63;  // w = head
    int lr = l & 15, lg = l >> 4;
    int h = w;
    int bh = b * Hn + h;
    int i = it * 16 + lr;  // row within batch

    const __bf16* qrow = qkvb + (size_t)bh * (Nn * HDn) + (size_t)i * HDn;
    bf16x8 qf0 = *(const bf16x8*)(qrow + lg * 8);
    bf16x8 qf1 = *(const bf16x8*)(qrow + 32 + lg * 8);

    const __bf16* kbase = qkvb + 1048576 + (size_t)bh * (Nn * HDn);
    f32x4 s[16];
#pragma unroll
    for (int jt = 0; jt < 16; jt++) {
        const __bf16* krow = kbase + (size_t)(jt * 16 + lr) * HDn;
        bf16x8 ka = *(const bf16x8*)(krow + lg * 8);
        bf16x8 kb = *(const bf16x8*)(krow + 32 + lg * 8);
        f32x4 acc = (f32x4){0.f, 0.f, 0.f, 0.f};
        acc = MFMA16(ka, qf0, acc);
        acc = MFMA16(kb, qf1, acc);
        s[jt] = acc;  // S[j = jt*16+lg*4+r][i = lr]
    }

    const float* brow = bias_eff + ((size_t)bh * Nn + i) * Nn;
    const unsigned int* mrow = (const unsigned int*)(knn + ((size_t)(b * Nn + i)) * Nn);
    float mx = -1e30f;
#pragma unroll
    for (int jt = 0; jt < 16; jt++) {
        f32x4 bi = *(const f32x4*)(brow + jt * 16 + lg * 4);
        unsigned int mk = mrow[jt * 4 + lg];
#pragma unroll
        for (int r = 0; r < 4; r++) {
            float v = fmaf(s[jt][r], 0.125f, bi[r]);
            v = ((mk >> (8 * r)) & 0xff) ? v : -1e9f;
            s[jt][r] = v;
            mx = fmaxf(mx, v);
        }
    }
    mx = fmaxf(mx, __shfl_xor(mx, 16, 64));
    mx = fmaxf(mx, __shfl_xor(mx, 32, 64));
    float sum = 0.0f;
#pragma unroll
    for (int jt = 0; jt < 16; jt++)
#pragma unroll
        for (int r = 0; r < 4; r++) {
            float e = __builtin_amdgcn_exp2f((s[jt][r] - mx) * 1.44269504f);
            s[jt][r] = e;
            sum += e;
        }
    sum += __shfl_xor(sum, 16, 64);
    sum += __shfl_xor(sum, 32, 64);
    float inv = 1.0f / sum;

    float* arow = attn_out + ((size_t)bh * Nn + i) * Nn;
#pragma unroll
    for (int jt = 0; jt < 16; jt++) {
        f32x4 o4;
#pragma unroll
        for (int r = 0; r < 4; r++) {
            float a = s[jt][r] * inv;
            s[jt][r] = a;
            o4[r] = a;
        }
        *(f32x4*)(arow + jt * 16 + lg * 4) = o4;
    }

    // PV: A-frags from global vT[bh][d][n]
    const __bf16* vT = qkvb + 2 * 1048576 + (size_t)bh * (HDn * Nn);
    f32x4 o[4];
#pragma unroll
    for (int dt = 0; dt < 4; dt++) o[dt] = (f32x4){0.f, 0.f, 0.f, 0.f};
    for (int half = 0; half < 2; half++) {
#pragma unroll
        for (int jr = 0; jr < 8; jr++) {
            int jt = half * 8 + jr;
            __bf16 pb[4];
#pragma unroll
            for (int r = 0; r < 4; r++) pb[r] = (__bf16)s[jt][r];
            *(uint2*)&Plds[w][lr][jr * 16 + lg * 4] = *(uint2*)pb;
        }
#pragma unroll
        for (int kk = 0; kk < 4; kk++) {
            bf16x8 pfrag = *(const bf16x8*)&Plds[w][lr][kk * 32 + lg * 8];
#pragma unroll
            for (int dt = 0; dt < 4; dt++) {
                bf16x8 vfrag = *(const bf16x8*)(vT + (size_t)(dt * 16 + lr) * Nn + half * 128 +
                                                kk * 32 + lg * 8);
                o[dt] = MFMA16(vfrag, pfrag, o[dt]);
            }
        }
    }

    // O -> htile[i_local][c]: col i = lr, row d = dt*16+lg*4+r ; c = h*64 + d
#pragma unroll
    for (int dt = 0; dt < 4; dt++) {
        __bf16 hb[4];
#pragma unroll
        for (int r = 0; r < 4; r++) hb[r] = (__bf16)o[dt][r];
        *(uint2*)&htile[lr][h * HDn + dt * 16 + lg * 4] = *(uint2*)hb;
    }
    __syncthreads();

    // proj: wave w -> out cols w*64..+64, rows = the block's 16 rows
    f32x4 pa[4];
#pragma unroll
    for (int ot = 0; ot < 4; ot++) pa[ot] = (f32x4){0.f, 0.f, 0.f, 0.f};
#pragma unroll
    for (int kc = 0; kc < 8; kc++) {
        bf16x8 af = *(const bf16x8*)&htile[lr][kc * 32 + lg * 8];
#pragma unroll
        for (int ot = 0; ot < 4; ot++) {
            bf16x8 bfr = *(const bf16x8*)(wpT + (size_t)(w * 64 + ot * 16 + lr) * Cn +
                                          kc * 32 + lg * 8);
            pa[ot] = MFMA16(af, bfr, pa[ot]);
        }
    }
#pragma unroll
    for (int ot = 0; ot < 4; ot++) {
        int oc = w * 64 + ot * 16 + lr;
        float bo = bp[oc];
#pragma unroll
        for (int r = 0; r < 4; r++) {
            int rowg = b * Nn + it * 16 + lg * 4 + r;
            size_t idx = (size_t)rowg * Cn + oc;
            xout[idx] = x[idx] + bo + pa[ot][r];
        }
    }
}

extern "C" void kernel_launch(void* const* d_in, const int* in_sizes, int n_in,
                              void* d_out, int out_size, void* d_ws, size_t ws_size,
                              hipStream_t stream) {
    const float* x       = (const float*)d_in[0];
    const float* lang    = (const float*)d_in[1];
    const float* centers = (const float*)d_in[2];
    const float* corners = (const float*)d_in[3];
    const int*   obj     = (const int*)d_in[4];
    const float* ln_g    = (const float*)d_in[5];
    const float* ln_b    = (const float*)d_in[6];
    const float* W_qkv   = (const float*)d_in[7];
    const float* b_qkv   = (const float*)d_in[8];
    const float* W_proj  = (const float*)d_in[9];
    const float* b_proj  = (const float*)d_in[10];
    const float* Wg1     = (const float*)d_in[11];
    const float* bg1     = (const float*)d_in[12];
    const float* Wg2     = (const float*)d_in[13];
    const float* bg2     = (const float*)d_in[14];
    const float* Wt1     = (const float*)d_in[15];
    const float* bt1     = (const float*)d_in[16];
    const float* Wt2     = (const float*)d_in[17];
    const float* bt2     = (const float*)d_in[18];
    const float* alpha   = (const float*)d_in[19];

    float* out = (float*)d_out;
    float* xout     = out;                 // BL*N*C
    float* attn     = out + 1048576;       // BL*H*N*N
    float* bias_eff = out + 5242880;       // BL*H*N*N

    __bf16* xnb   = (__bf16*)d_ws;              // 1,048,576 bf16
    __bf16* qkvb  = xnb + 1048576;              // q,k: [bh][n][d]; v: [bh][d][n]
    __bf16* wqT   = qkvb + 3145728;             // 196,608 bf16
    __bf16* wpT   = wqT + 196608;               // 65,536 bf16
    float*  sizes = (float*)(wpT + 65536);      // 12,288 f32
    float*  headw = sizes + 12288;              // 64 f32
    unsigned char* knn = (unsigned char*)(headw + 64);  // 1 MiB

    k_prep<<<5216, 256, 0, stream>>>(x, ln_g, ln_b, xnb, centers, obj, knn, corners, sizes,
                                     lang, Wt1, bt1, Wt2, bt2, headw, W_qkv, wqT, W_proj, wpT);
    k_heavy<<<4864, 256, 0, stream>>>(centers, sizes, Wg1, bg1, Wg2, bg2, headw, alpha,
                                      bias_eff, xnb, wqT, b_qkv, qkvb);
    k_attn<<<256, 256, 0, stream>>>(qkvb, bias_eff, knn, attn, wpT, b_proj, x, xout);
}

// Round 14
// 119.778 us; speedup vs baseline: 1.0678x; 1.0678x over previous
//
#include <hip/hip_runtime.h>
#include <math.h>

#define BLn 16
#define Nn 256
#define Tn 32
#define Cn 256
#define Hn 4
#define HDn 64
#define KREL 32

typedef float f32x4 __attribute__((ext_vector_type(4)));
typedef __bf16 bf16x8 __attribute__((ext_vector_type(8)));
typedef _Float16 f16x4 __attribute__((ext_vector_type(4)));
typedef _Float16 f16x2 __attribute__((ext_vector_type(2)));

#define MFMA16(a, b, c) __builtin_amdgcn_mfma_f32_16x16x32_bf16(a, b, c, 0, 0, 0)
#define MFMA16H(a, b, c) __builtin_amdgcn_mfma_f32_16x16x16f16(a, b, c, 0, 0, 0)

__device__ __forceinline__ float gelu_exact(float x) {
    return 0.5f * x * (1.0f + erff(x * 0.70710678118654752440f));
}

// packed-f16 gelu (validated r8/r12, absmax 0.031)
__device__ __forceinline__ f16x2 gelu_pk(f16x2 x) {
    const f16x2 P4 = {(_Float16)4.0f, (_Float16)4.0f};
    const f16x2 M4 = {(_Float16)-4.0f, (_Float16)-4.0f};
    const f16x2 C0 = {(_Float16)0.833076f, (_Float16)0.833076f};
    const f16x2 C1 = {(_Float16)-0.139388f, (_Float16)-0.139388f};
    const f16x2 C2 = {(_Float16)0.013040f, (_Float16)0.013040f};
    const f16x2 C3 = {(_Float16)-0.000413f, (_Float16)-0.000413f};
    const f16x2 HF = {(_Float16)0.5f, (_Float16)0.5f};
    const f16x2 ONE = {(_Float16)1.0f, (_Float16)1.0f};
    const f16x2 ZERO = {(_Float16)0.0f, (_Float16)0.0f};
    f16x2 xc = __builtin_elementwise_min(__builtin_elementwise_max(x, M4), P4);
    f16x2 v = xc * xc;
    f16x2 w = C3 * v + C2;
    w = w * v + C1;
    w = w * v + C0;
    f16x2 t = w * xc;
    f16x2 s = t * HF + HF;
    s = __builtin_elementwise_min(__builtin_elementwise_max(s, ZERO), ONE);
    return x * s;
}

// ---------------- fused prep: ln(wave-per-row) | knn | sizes | headw | W transposes ----
__global__ void __launch_bounds__(256) k_prep(
    const float* __restrict__ x, const float* __restrict__ ln_g, const float* __restrict__ ln_b,
    __bf16* __restrict__ xnb, const float* __restrict__ centers, const int* __restrict__ obj,
    unsigned char* __restrict__ knn, const float* __restrict__ corners,
    float* __restrict__ sizes, const float* __restrict__ lang, const float* __restrict__ Wt1,
    const float* __restrict__ bt1, const float* __restrict__ Wt2, const float* __restrict__ bt2,
    float* __restrict__ headw, const float* __restrict__ W_qkv, __bf16* __restrict__ wqT,
    const float* __restrict__ W_proj, __bf16* __restrict__ wpT) {
    __shared__ float4 d4[64];
    __shared__ float sm1[Nn];
    __shared__ float T[64][65];
    float* sm0 = (float*)d4;
    int blk = blockIdx.x;
    int tid = threadIdx.x;

    if (blk < 1024) {  // ---- LayerNorm: 1 wave = 1 row, no LDS, no barriers ----
        int row = blk * 4 + (tid >> 6);
        int l = tid & 63;
        float4 v = ((const float4*)(x + (size_t)row * Cn))[l];
        float s = v.x + v.y + v.z + v.w;
        float q = v.x * v.x + v.y * v.y + v.z * v.z + v.w * v.w;
        for (int m = 32; m > 0; m >>= 1) {
            s += __shfl_xor(s, m, 64);
            q += __shfl_xor(q, m, 64);
        }
        float mu = s * (1.0f / Cn);
        float var = q * (1.0f / Cn) - mu * mu;
        float r = rsqrtf(var + 1e-5f);
        float4 g = ((const float4*)ln_g)[l];
        float4 be = ((const float4*)ln_b)[l];
        __bf16 ob[4];
        ob[0] = (__bf16)((v.x - mu) * r * g.x + be.x);
        ob[1] = (__bf16)((v.y - mu) * r * g.y + be.y);
        ob[2] = (__bf16)((v.z - mu) * r * g.z + be.z);
        ob[3] = (__bf16)((v.w - mu) * r * g.w + be.w);
        *(uint2*)(xnb + (size_t)row * Cn + l * 4) = *(uint2*)ob;
    } else if (blk < 5120) {  // ---- KNN + pair mask ----
        int bi = blk - 1024;
        int b = bi >> 8, i = bi & 255;
        int j = tid;
        float cx = centers[(b * Nn + i) * 3 + 0];
        float cy = centers[(b * Nn + i) * 3 + 1];
        float cz = centers[(b * Nn + i) * 3 + 2];
        float dx = centers[(b * Nn + j) * 3 + 0] - cx;
        float dy = centers[(b * Nn + j) * 3 + 1] - cy;
        float dz = centers[(b * Nn + j) * 3 + 2] - cz;
        float dd = sqrtf(dx * dx + dy * dy + dz * dz);
        sm0[j] = dd;
        __syncthreads();
        int rank = 0;
        for (int t4 = 0; t4 < 64; t4++) {
            float4 o = d4[t4];
            int t = t4 * 4;
            rank += (o.x < dd) || (o.x == dd && t + 0 < j);
            rank += (o.y < dd) || (o.y == dd && t + 1 < j);
            rank += (o.z < dd) || (o.z == dd && t + 2 < j);
            rank += (o.w < dd) || (o.w == dd && t + 3 < j);
        }
        bool m = (rank < KREL);
        m = m && (obj[b * Nn + i] != 0) && (obj[b * Nn + j] != 0);
        knn[(size_t)bi * Nn + j] = m ? 1 : 0;
    } else if (blk < 5136) {  // ---- sizes ----
        int b = blk - 5120, n = tid;
        const float* p = corners + (size_t)((b * Nn + n) * 8) * 3;
        float mn[3] = {1e30f, 1e30f, 1e30f}, mx[3] = {-1e30f, -1e30f, -1e30f};
        for (int v = 0; v < 8; v++)
            for (int d = 0; d < 3; d++) {
                float t = p[v * 3 + d];
                mn[d] = fminf(mn[d], t);
                mx[d] = fmaxf(mx[d], t);
            }
        for (int d = 0; d < 3; d++) sizes[(b * Nn + n) * 3 + d] = mx[d] - mn[d];
    } else if (blk < 5152) {  // ---- head weights ----
        int b = blk - 5136, c = tid;
        float s = 0.0f;
        for (int t = 0; t < Tn; t++) s += lang[((size_t)b * Tn + t) * Cn + c];
        sm0[c] = s * (1.0f / Tn);
        __syncthreads();
        float acc = bt1[c];
        for (int i = 0; i < Cn; i++) acc += sm0[i] * Wt1[i * Cn + c];
        sm1[c] = gelu_exact(acc);
        __syncthreads();
        if (c < Hn) {
            float a = bt2[c];
            for (int i = 0; i < Cn; i++) a += sm1[i] * Wt2[i * Hn + c];
            headw[b * Hn + c] = 1.0f / (1.0f + expf(-a));
        }
    } else if (blk < 5200) {  // ---- W_qkv^T -> bf16 [768 o][256 k] ----
        int t = blk - 5152;
        int kt = t & 3, ot = t >> 2;
        for (int itr = 0; itr < 16; itr++) {
            int idx = itr * 256 + tid;
            int r = idx >> 6, c = idx & 63;
            T[r][c] = W_qkv[(size_t)(kt * 64 + r) * 768 + ot * 64 + c];
        }
        __syncthreads();
        for (int itr = 0; itr < 16; itr++) {
            int idx = itr * 256 + tid;
            int r = idx >> 6, c = idx & 63;
            wqT[(size_t)(ot * 64 + r) * 256 + kt * 64 + c] = (__bf16)T[c][r];
        }
    } else {  // ---- W_proj^T -> bf16 [256 o][256 k] ----
        int t = blk - 5200;
        int kt = t & 3, ot = t >> 2;
        for (int itr = 0; itr < 16; itr++) {
            int idx = itr * 256 + tid;
            int r = idx >> 6, c = idx & 63;
            T[r][c] = W_proj[(size_t)(kt * 64 + r) * 256 + ot * 64 + c];
        }
        __syncthreads();
        for (int itr = 0; itr < 16; itr++) {
            int idx = itr * 256 + tid;
            int r = idx >> 6, c = idx & 63;
            wpT[(size_t)(ot * 64 + r) * 256 + kt * 64 + c] = (__bf16)T[c][r];
        }
    }
}

// ---------------- fused heavy kernel (EXACT r8 config): geombias + qkv ----------------
__global__ void __launch_bounds__(256, 4) k_heavy(
    const float* __restrict__ centers, const float* __restrict__ sizes,
    const float* __restrict__ Wg1, const float* __restrict__ bg1,
    const float* __restrict__ Wg2, const float* __restrict__ bg2,
    const float* __restrict__ headw, const float* __restrict__ alphap,
    float* __restrict__ bias_eff, const __bf16* __restrict__ xnb,
    const __bf16* __restrict__ wqT, const float* __restrict__ bqkv,
    __bf16* __restrict__ qkvb) {
    __shared__ __align__(16) _Float16 fT[Nn][20];   // [j][k]  10240 B
    __shared__ __align__(16) _Float16 W1T[Cn][20];  // [c][k]  10240 B
    __shared__ __align__(16) _Float16 W2T[16][264]; // [h][c] rows 4..15 zero, 8448 B

    int blk = blockIdx.x;
    int tid = threadIdx.x;

    if (blk >= 4096) {
        // ================= QKV path (bf16 MFMA, K=32) =================
        int t = blk - 4096;
        int ib = t & 63, y = t >> 6;
        int w = tid >> 6, l = tid & 63, lr = l & 15, lg = l >> 4;
        const __bf16* arow = xnb + (size_t)(ib * 64 + w * 16 + lr) * Cn;

        f32x4 acc[4];
#pragma unroll
        for (int ot = 0; ot < 4; ot++) acc[ot] = (f32x4){0.f, 0.f, 0.f, 0.f};
#pragma unroll
        for (int kc = 0; kc < 8; kc++) {
            bf16x8 af = *(const bf16x8*)(arow + kc * 32 + lg * 8);
#pragma unroll
            for (int ot = 0; ot < 4; ot++) {
                bf16x8 bfr = *(const bf16x8*)(wqT + (size_t)(y * 64 + ot * 16 + lr) * Cn +
                                              kc * 32 + lg * 8);
                acc[ot] = MFMA16(af, bfr, acc[ot]);
            }
        }
        int seg = y >> 2, h = y & 3;
        __bf16* segp = qkvb + (size_t)seg * 1048576;
#pragma unroll
        for (int ot = 0; ot < 4; ot++) {
            float bo = bqkv[y * 64 + ot * 16 + lr];
#pragma unroll
            for (int r = 0; r < 4; r++) {
                int ig = ib * 64 + w * 16 + lg * 4 + r;
                int b = ig >> 8, n = ig & 255;
                segp[(((size_t)(b * Hn + h)) * Nn + n) * HDn + ot * 16 + lr] =
                    (__bf16)(acc[ot][r] + bo);
            }
        }
        return;
    }

    // ================= geombias path =================
    int b = blk >> 8, i = blk & 255;

    // ---- stage weights (thread = c) ----
    {
        int c = tid;
        _Float16 t1[20];
#pragma unroll
        for (int k = 0; k < 12; k++) t1[k] = (_Float16)Wg1[k * Cn + c];
        t1[12] = (_Float16)bg1[c];
#pragma unroll
        for (int k = 13; k < 20; k++) t1[k] = (_Float16)0.f;
#pragma unroll
        for (int q = 0; q < 5; q++) *(uint2*)&W1T[c][q * 4] = *(uint2*)&t1[q * 4];
#pragma unroll
        for (int h = 0; h < 16; h++)
            W2T[h][c] = (h < Hn) ? (_Float16)Wg2[c * Hn + h] : (_Float16)0.f;
    }
    // ---- features for pair (i, j=tid) ----
    {
        int j = tid;
        float ci0 = centers[(b * Nn + i) * 3 + 0];
        float ci1 = centers[(b * Nn + i) * 3 + 1];
        float ci2 = centers[(b * Nn + i) * 3 + 2];
        float si0 = sizes[(b * Nn + i) * 3 + 0];
        float si1 = sizes[(b * Nn + i) * 3 + 1];
        float si2 = sizes[(b * Nn + i) * 3 + 2];
        float cj0 = centers[(b * Nn + j) * 3 + 0];
        float cj1 = centers[(b * Nn + j) * 3 + 1];
        float cj2 = centers[(b * Nn + j) * 3 + 2];
        float sj0 = sizes[(b * Nn + j) * 3 + 0];
        float sj1 = sizes[(b * Nn + j) * 3 + 1];
        float sj2 = sizes[(b * Nn + j) * 3 + 2];
        float rx = cj0 - ci0, ry = cj1 - ci1, rz = cj2 - ci2;
        float h2 = rx * rx + ry * ry;
        float dist = sqrtf(h2 + rz * rz);
        float horiz = sqrtf(h2);
        float f[16];
        f[0] = rx; f[1] = ry; f[2] = rz;
        f[3] = dist; f[4] = horiz;
        f[5] = rz / (dist + 1e-6f);
        f[6] = sj0 - si0; f[7] = sj1 - si1; f[8] = sj2 - si2;
        f[9] = sj0 / (si0 + 1e-6f);
        f[10] = sj1 / (si1 + 1e-6f);
        f[11] = sj2 / (si2 + 1e-6f);
        f[12] = 1.0f;  // bias feature -> W1 row 12 = bg1
        _Float16 tf[20];
#pragma unroll
        for (int k = 0; k < 13; k++) tf[k] = (_Float16)f[k];
#pragma unroll
        for (int k = 13; k < 20; k++) tf[k] = (_Float16)0.f;
#pragma unroll
        for (int q = 0; q < 5; q++) *(uint2*)&fT[j][q * 4] = *(uint2*)&tf[q * 4];
    }
    __syncthreads();

    int w = tid >> 6, l = tid & 63;
    int lr = l & 15, lg = l >> 4;
    int jw = w * 64;

    f32x4 zero4 = {0.f, 0.f, 0.f, 0.f};

    // feature B-frags (K=16): lane holds col j = jw+jt*16+lr, k = lg*4+e
    f16x4 bf_[4];
#pragma unroll
    for (int jt = 0; jt < 4; jt++) bf_[jt] = *(const f16x4*)&fT[jw + jt * 16 + lr][lg * 4];

    f32x4 pacc[4];
#pragma unroll
    for (int jt = 0; jt < 4; jt++) pacc[jt] = zero4;

#pragma unroll 2
    for (int cw = 0; cw < 16; cw++) {  // 16 c-windows of K=16
        int cbase = cw * 16;
        // L1 A-frag: row c = cbase+lr, k = lg*4+e
        f16x4 aw = *(const f16x4*)&W1T[cbase + lr][lg * 4];
        // L2 B-frag: k c = cbase+lg*4+e, col h = lr (rows 4..15 of W2T are zero)
        f16x4 b2 = *(const f16x4*)&W2T[lr][cbase + lg * 4];
#pragma unroll
        for (int jt = 0; jt < 4; jt++) {
            // L1: D col j = lr, row c = lg*4+r  == L2 A-frag layout (row j, k c)
            f32x4 acc = MFMA16H(aw, bf_[jt], zero4);
            f16x2 h01 = __builtin_bit_cast(f16x2, __builtin_amdgcn_cvt_pkrtz(acc[0], acc[1]));
            f16x2 h23 = __builtin_bit_cast(f16x2, __builtin_amdgcn_cvt_pkrtz(acc[2], acc[3]));
            h01 = gelu_pk(h01);
            h23 = gelu_pk(h23);
            f16x4 ga;
            ga[0] = h01[0]; ga[1] = h01[1]; ga[2] = h23[0]; ga[3] = h23[1];
            pacc[jt] = MFMA16H(ga, b2, pacc[jt]);
        }
    }

    float alpha = alphap[0];
    if (lr < Hn) {  // D: col(h)=lr, row(j-local)=lg*4+r
        float hw_ = headw[b * Hn + lr];
        float bg = bg2[lr];
        float* dst = bias_eff + (((size_t)(b * Hn + lr)) * Nn + i) * Nn;
#pragma unroll
        for (int jt = 0; jt < 4; jt++) {
            f32x4 o4;
#pragma unroll
            for (int r = 0; r < 4; r++) o4[r] = alpha * hw_ * (pacc[jt][r] + bg);
            *(f32x4*)&dst[jw + jt * 16 + lg * 4] = o4;
        }
    }
}

// ---------------- attention: MFMA flash-style, 64 i-rows per block (EXACT r8) ----------
__global__ void __launch_bounds__(256) k_attn(const __bf16* __restrict__ qkvb,
                                              const float* __restrict__ bias_eff,
                                              const unsigned char* __restrict__ knn,
                                              float* __restrict__ attn_out,
                                              __bf16* __restrict__ houtb) {
    __shared__ __bf16 Vt[64][264];
    __shared__ __bf16 Plds[4][16][136];
    int blk = blockIdx.x;
    int bh = blk >> 2, it = blk & 3;
    int b = bh >> 2, h = bh & 3;
    int tid = threadIdx.x;

    const __bf16* vbase = qkvb + 2 * 1048576 + (size_t)bh * (Nn * HDn);
    {
        int j = tid;
#pragma unroll
        for (int c8 = 0; c8 < 8; c8++) {
            bf16x8 v8 = *(const bf16x8*)(vbase + (size_t)j * HDn + c8 * 8);
#pragma unroll
            for (int e = 0; e < 8; e++) Vt[c8 * 8 + e][j] = v8[e];
        }
    }
    __syncthreads();

    int w = tid >> 6, l = tid & 63;
    int lr = l & 15, lg = l >> 4;
    int i_glob = it * 64 + w * 16 + lr;

    const __bf16* qrow = qkvb + (size_t)bh * (Nn * HDn) + (size_t)i_glob * HDn;
    bf16x8 qf0 = *(const bf16x8*)(qrow + lg * 8);
    bf16x8 qf1 = *(const bf16x8*)(qrow + 32 + lg * 8);

    const __bf16* kbase = qkvb + 1048576 + (size_t)bh * (Nn * HDn);
    f32x4 s[16];
#pragma unroll
    for (int jt = 0; jt < 16; jt++) {
        const __bf16* krow = kbase + (size_t)(jt * 16 + lr) * HDn;
        bf16x8 ka = *(const bf16x8*)(krow + lg * 8);
        bf16x8 kb = *(const bf16x8*)(krow + 32 + lg * 8);
        f32x4 acc = (f32x4){0.f, 0.f, 0.f, 0.f};
        acc = MFMA16(ka, qf0, acc);
        acc = MFMA16(kb, qf1, acc);
        s[jt] = acc;
    }

    const float* brow = bias_eff + ((size_t)bh * Nn + i_glob) * Nn;
    const unsigned int* mrow = (const unsigned int*)(knn + ((size_t)(b * Nn + i_glob)) * Nn);
    float mx = -1e30f;
#pragma unroll
    for (int jt = 0; jt < 16; jt++) {
        f32x4 bi = *(const f32x4*)(brow + jt * 16 + lg * 4);
        unsigned int mk = mrow[jt * 4 + lg];
#pragma unroll
        for (int r = 0; r < 4; r++) {
            float v = fmaf(s[jt][r], 0.125f, bi[r]);
            v = ((mk >> (8 * r)) & 0xff) ? v : -1e9f;
            s[jt][r] = v;
            mx = fmaxf(mx, v);
        }
    }
    mx = fmaxf(mx, __shfl_xor(mx, 16, 64));
    mx = fmaxf(mx, __shfl_xor(mx, 32, 64));
    float sum = 0.0f;
#pragma unroll
    for (int jt = 0; jt < 16; jt++)
#pragma unroll
        for (int r = 0; r < 4; r++) {
            float e = __builtin_amdgcn_exp2f((s[jt][r] - mx) * 1.44269504f);
            s[jt][r] = e;
            sum += e;
        }
    sum += __shfl_xor(sum, 16, 64);
    sum += __shfl_xor(sum, 32, 64);
    float inv = 1.0f / sum;

    float* arow = attn_out + ((size_t)bh * Nn + i_glob) * Nn;
#pragma unroll
    for (int jt = 0; jt < 16; jt++) {
        f32x4 o4;
#pragma unroll
        for (int r = 0; r < 4; r++) {
            float a = s[jt][r] * inv;
            s[jt][r] = a;
            o4[r] = a;
        }
        *(f32x4*)(arow + jt * 16 + lg * 4) = o4;
    }

    f32x4 o[4];
#pragma unroll
    for (int dt = 0; dt < 4; dt++) o[dt] = (f32x4){0.f, 0.f, 0.f, 0.f};
    for (int half = 0; half < 2; half++) {
#pragma unroll
        for (int jr = 0; jr < 8; jr++) {
            int jt = half * 8 + jr;
            __bf16 pb[4];
#pragma unroll
            for (int r = 0; r < 4; r++) pb[r] = (__bf16)s[jt][r];
            *(uint2*)&Plds[w][lr][jr * 16 + lg * 4] = *(uint2*)pb;
        }
#pragma unroll
        for (int kk = 0; kk < 4; kk++) {
            bf16x8 pfrag = *(const bf16x8*)&Plds[w][lr][kk * 32 + lg * 8];
#pragma unroll
            for (int dt = 0; dt < 4; dt++) {
                bf16x8 vfrag = *(const bf16x8*)&Vt[dt * 16 + lr][half * 128 + kk * 32 + lg * 8];
                o[dt] = MFMA16(vfrag, pfrag, o[dt]);
            }
        }
    }

    __bf16* hrow = houtb + ((size_t)(b * Nn + i_glob)) * Cn + h * HDn;
#pragma unroll
    for (int dt = 0; dt < 4; dt++) {
        __bf16 hb[4];
#pragma unroll
        for (int r = 0; r < 4; r++) hb[r] = (__bf16)o[dt][r];
        *(uint2*)(hrow + dt * 16 + lg * 4) = *(uint2*)hb;
    }
}

// ---------------- output projection + residual: MFMA (EXACT r8) ----------------
__global__ void __launch_bounds__(256) k_proj(const __bf16* __restrict__ houtb,
                                              const __bf16* __restrict__ wpT,
                                              const float* __restrict__ bp,
                                              const float* __restrict__ x,
                                              float* __restrict__ xout) {
    int ib = blockIdx.x, y = blockIdx.y;
    int tid = threadIdx.x;
    int w = tid >> 6, l = tid & 63, lr = l & 15, lg = l >> 4;
    const __bf16* arow = houtb + (size_t)(ib * 64 + w * 16 + lr) * Cn;

    f32x4 acc[4];
#pragma unroll
    for (int ot = 0; ot < 4; ot++) acc[ot] = (f32x4){0.f, 0.f, 0.f, 0.f};
#pragma unroll
    for (int kc = 0; kc < 8; kc++) {
        bf16x8 af = *(const bf16x8*)(arow + kc * 32 + lg * 8);
#pragma unroll
        for (int ot = 0; ot < 4; ot++) {
            bf16x8 bfr = *(const bf16x8*)(wpT + (size_t)(y * 64 + ot * 16 + lr) * Cn +
                                          kc * 32 + lg * 8);
            acc[ot] = MFMA16(af, bfr, acc[ot]);
        }
    }
#pragma unroll
    for (int ot = 0; ot < 4; ot++) {
        int o = y * 64 + ot * 16 + lr;
        float bo = bp[o];
#pragma unroll
        for (int r = 0; r < 4; r++) {
            int ig = ib * 64 + w * 16 + lg * 4 + r;
            size_t idx = (size_t)ig * Cn + o;
            xout[idx] = x[idx] + bo + acc[ot][r];
        }
    }
}

extern "C" void kernel_launch(void* const* d_in, const int* in_sizes, int n_in,
                              void* d_out, int out_size, void* d_ws, size_t ws_size,
                              hipStream_t stream) {
    const float* x       = (const float*)d_in[0];
    const float* lang    = (const float*)d_in[1];
    const float* centers = (const float*)d_in[2];
    const float* corners = (const float*)d_in[3];
    const int*   obj     = (const int*)d_in[4];
    const float* ln_g    = (const float*)d_in[5];
    const float* ln_b    = (const float*)d_in[6];
    const float* W_qkv   = (const float*)d_in[7];
    const float* b_qkv   = (const float*)d_in[8];
    const float* W_proj  = (const float*)d_in[9];
    const float* b_proj  = (const float*)d_in[10];
    const float* Wg1     = (const float*)d_in[11];
    const float* bg1     = (const float*)d_in[12];
    const float* Wg2     = (const float*)d_in[13];
    const float* bg2     = (const float*)d_in[14];
    const float* Wt1     = (const float*)d_in[15];
    const float* bt1     = (const float*)d_in[16];
    const float* Wt2     = (const float*)d_in[17];
    const float* bt2     = (const float*)d_in[18];
    const float* alpha   = (const float*)d_in[19];

    float* out = (float*)d_out;
    float* xout     = out;                 // BL*N*C
    float* attn     = out + 1048576;       // BL*H*N*N
    float* bias_eff = out + 5242880;       // BL*H*N*N

    __bf16* xnb   = (__bf16*)d_ws;              // 1,048,576 bf16
    __bf16* qkvb  = xnb + 1048576;              // 3 x 1,048,576 bf16 (q,k,v)
    __bf16* houtb = qkvb + 3145728;             // 1,048,576 bf16
    __bf16* wqT   = houtb + 1048576;            // 196,608 bf16
    __bf16* wpT   = wqT + 196608;               // 65,536 bf16
    float*  sizes = (float*)(wpT + 65536);      // 12,288 f32
    float*  headw = sizes + 12288;              // 64 f32
    unsigned char* knn = (unsigned char*)(headw + 64);  // 1 MiB

    k_prep<<<5216, 256, 0, stream>>>(x, ln_g, ln_b, xnb, centers, obj, knn, corners, sizes,
                                     lang, Wt1, bt1, Wt2, bt2, headw, W_qkv, wqT, W_proj, wpT);
    k_heavy<<<4864, 256, 0, stream>>>(centers, sizes, Wg1, bg1, Wg2, bg2, headw, alpha,
                                      bias_eff, xnb, wqT, b_qkv, qkvb);
    k_attn<<<256, 256, 0, stream>>>(qkvb, bias_eff, knn, attn, houtb);
    k_proj<<<dim3(64, 4), 256, 0, stream>>>(houtb, wpT, b_proj, x, xout);
}